// Round 2
// baseline (452.320 us; speedup 1.0000x reference)
//
#include <hip/hip_runtime.h>

#define D 64

typedef float f4v __attribute__((ext_vector_type(4)));

static __device__ __forceinline__ void nt_store4(float* p, float4 v) {
  f4v t; t[0] = v.x; t[1] = v.y; t[2] = v.z; t[3] = v.w;
  __builtin_nontemporal_store(t, reinterpret_cast<f4v*>(p));
}

// ---------------- structs ----------------
struct ReduceArgs {
  const int* uids; const int* iids;
  const float* uemb; const float* iemb;
  const float* wu[6]; const float* wi[6];   // per-side w vectors (slot order: uu b,c,p then iu b,c,p / ui b,c,p then ii b,c,p)
  float* S;                                  // [12][64] raw sums over e (un-scaled)
  int n_user, n_item, blocksU;
};

struct BuildArgs {
  const float* S;
  const float* w1[12];   // q order: uu b,c,p | ui b,c,p | ii b,c,p | iu b,c,p
  float* U;              // [12][64]  U_q = 2.5e-4 * W_q * (S[sslot[q]] @ w1_q)
  int sslot[12];
  float coef[12];
};

struct FinalArgs {
  const int* uids; const int* iids;
  const float* uemb; const float* iemb;
  const float* U;                // [12][64]: x-side slots 0..5, y-side slots 6..11
  const float* wx[6];            // uu b,c,p, ui b,c,p
  const float* wy[6];            // ii b,c,p, iu b,c,p
  float* out;
  int n_user, n_item, blocksU;
};

// ---------------- kernel 0: zero S accumulator + copy edge outputs ----------------
__global__ __launch_bounds__(256) void k_init(float* S, float* edges,
                                              const float* be, const float* ce, const float* pe) {
  const int t = threadIdx.x;
  S[t] = 0.f; S[t + 256] = 0.f; S[t + 512] = 0.f;
  if (t < 64)       edges[t] = be[t];
  else if (t < 128) edges[t] = ce[t - 64];
  else if (t < 192) edges[t] = pe[t - 128];
}

// ---------------- kernel 1: S[j] = sum_rows (e . w_j) * e  (raw e) ----------------
// R5: 16 rows/wave-iteration (four independent gather chains) + next-iter id
// prefetch. ids are arange in this workload so the "gather" is streaming, but
// 4 chains halves loop overhead and doubles bytes in flight per wave.
__global__ __launch_bounds__(256) void k_reduce(ReduceArgs a) {
  const int bx = (int)blockIdx.x;
  const bool us = bx < a.blocksU;
  const int*   __restrict__ ids = us ? a.uids : a.iids;
  const float* __restrict__ emb = us ? a.uemb : a.iemb;
  float* __restrict__ Sout = a.S + (us ? 0 : 6 * D);
  const int n   = us ? a.n_user : a.n_item;
  const int nb  = us ? a.blocksU : ((int)gridDim.x - a.blocksU);
  const int bid = us ? bx : bx - a.blocksU;

  const int tid   = (int)threadIdx.x;
  const int lane  = tid & 63;
  const int wave  = tid >> 6;
  const int chunk = lane & 15;   // which float4 of the row
  const int rsub  = lane >> 4;   // which of 4 rows this wave covers (per quarter-step)

  float4 wv[6];
  #pragma unroll
  for (int j = 0; j < 6; ++j) {
    const float* wp = us ? a.wu[j] : a.wi[j];
    wv[j] = reinterpret_cast<const float4*>(wp)[chunk];
  }

  float4 acc[6];
  #pragma unroll
  for (int j = 0; j < 6; ++j) acc[j] = make_float4(0.f, 0.f, 0.f, 0.f);

  const int wavesTotal = nb * 4;
  const int waveId = bid * 4 + wave;
  const int stride = wavesTotal * 16;
  int row = waveId * 16 + rsub;
  int id0 = 0, id1 = 0, id2 = 0, id3 = 0;
  if (row < n) {
    id0 = ids[row];
    if (row + 4 < n)  id1 = ids[row + 4];
    if (row + 8 < n)  id2 = ids[row + 8];
    if (row + 12 < n) id3 = ids[row + 12];
  }

  while (row < n) {
    const int nxt = row + stride;
    const bool h1 = (row + 4) < n;          // uniform within each 16-lane group
    const bool h2 = (row + 8) < n;
    const bool h3 = (row + 12) < n;
    const float4 v0 = reinterpret_cast<const float4*>(emb + (size_t)id0 * D)[chunk];
    float4 v1 = make_float4(0.f, 0.f, 0.f, 0.f);
    float4 v2 = make_float4(0.f, 0.f, 0.f, 0.f);
    float4 v3 = make_float4(0.f, 0.f, 0.f, 0.f);
    if (h1) v1 = reinterpret_cast<const float4*>(emb + (size_t)id1 * D)[chunk];
    if (h2) v2 = reinterpret_cast<const float4*>(emb + (size_t)id2 * D)[chunk];
    if (h3) v3 = reinterpret_cast<const float4*>(emb + (size_t)id3 * D)[chunk];
    // prefetch next iteration's ids while this iteration computes
    if (nxt < n) {
      id0 = ids[nxt];
      if (nxt + 4 < n)  id1 = ids[nxt + 4];
      if (nxt + 8 < n)  id2 = ids[nxt + 8];
      if (nxt + 12 < n) id3 = ids[nxt + 12];
    }
    #pragma unroll
    for (int j = 0; j < 6; ++j) {
      float d0 = fmaf(v0.x, wv[j].x, fmaf(v0.y, wv[j].y, fmaf(v0.z, wv[j].z, v0.w * wv[j].w)));
      float d1 = fmaf(v1.x, wv[j].x, fmaf(v1.y, wv[j].y, fmaf(v1.z, wv[j].z, v1.w * wv[j].w)));
      float d2 = fmaf(v2.x, wv[j].x, fmaf(v2.y, wv[j].y, fmaf(v2.z, wv[j].z, v2.w * wv[j].w)));
      float d3 = fmaf(v3.x, wv[j].x, fmaf(v3.y, wv[j].y, fmaf(v3.z, wv[j].z, v3.w * wv[j].w)));
      d0 += __shfl_xor(d0, 1);  d1 += __shfl_xor(d1, 1);  d2 += __shfl_xor(d2, 1);  d3 += __shfl_xor(d3, 1);
      d0 += __shfl_xor(d0, 2);  d1 += __shfl_xor(d1, 2);  d2 += __shfl_xor(d2, 2);  d3 += __shfl_xor(d3, 2);
      d0 += __shfl_xor(d0, 4);  d1 += __shfl_xor(d1, 4);  d2 += __shfl_xor(d2, 4);  d3 += __shfl_xor(d3, 4);
      d0 += __shfl_xor(d0, 8);  d1 += __shfl_xor(d1, 8);  d2 += __shfl_xor(d2, 8);  d3 += __shfl_xor(d3, 8);
      acc[j].x = fmaf(d3, v3.x, fmaf(d2, v2.x, fmaf(d1, v1.x, fmaf(d0, v0.x, acc[j].x))));
      acc[j].y = fmaf(d3, v3.y, fmaf(d2, v2.y, fmaf(d1, v1.y, fmaf(d0, v0.y, acc[j].y))));
      acc[j].z = fmaf(d3, v3.z, fmaf(d2, v2.z, fmaf(d1, v1.z, fmaf(d0, v0.z, acc[j].z))));
      acc[j].w = fmaf(d3, v3.w, fmaf(d2, v2.w, fmaf(d1, v1.w, fmaf(d0, v0.w, acc[j].w))));
    }
    row = nxt;
  }

  #pragma unroll
  for (int j = 0; j < 6; ++j) {
    acc[j].x += __shfl_xor(acc[j].x, 16); acc[j].x += __shfl_xor(acc[j].x, 32);
    acc[j].y += __shfl_xor(acc[j].y, 16); acc[j].y += __shfl_xor(acc[j].y, 32);
    acc[j].z += __shfl_xor(acc[j].z, 16); acc[j].z += __shfl_xor(acc[j].z, 32);
    acc[j].w += __shfl_xor(acc[j].w, 16); acc[j].w += __shfl_xor(acc[j].w, 32);
  }

  __shared__ __align__(16) float red[4][6][D];
  if (lane < 16) {
    #pragma unroll
    for (int j = 0; j < 6; ++j)
      reinterpret_cast<float4*>(&red[wave][j][0])[chunk] = acc[j];
  }
  __syncthreads();
  // BUGFIX (R2->R3): 384 (j,e) pairs but only 256 threads — previous
  // `if (tid < 384)` never emitted j=4,5, leaving S slots 4,5 / 10,11 zero
  // (exactly the cart/pv iu+ii slots -> y_out err 32.74, x_out unaffected).
  for (int t = tid; t < 384; t += 256) {
    const int j = t >> 6, e = t & 63;
    const float s = red[0][j][e] + red[1][j][e] + red[2][j][e] + red[3][j][e];
    atomicAdd(&Sout[j * D + e], s);
  }
}

// ---------------- kernel 2: U_q = coef_q * (S[sslot_q] @ w1_q)  (12 blocks x 64 thr) ----------------
__global__ __launch_bounds__(64) void k_build(BuildArgs a) {
  const int q = (int)blockIdx.x;
  const int d = (int)threadIdx.x;
  const float* __restrict__ w1 = a.w1[q];
  const float* __restrict__ Sv = a.S + a.sslot[q] * D;
  float s = 0.f;
  for (int k = 0; k < D; ++k) s = fmaf(Sv[k], w1[k * D + d], s);
  a.U[q * D + d] = a.coef[q] * s;
}

// ---------------- kernel 3: out_row = 0.05*e + sum_q (e . w_q) * U_q  (rank-6) ----------------
// R5: grid shrunk 2048 -> 1024 blocks (384 user / 640 item, preserving the
// exact 3:5 row ratio). At ~96 VGPR the device holds ~1024-1280 blocks
// co-resident; 2048 blocks was ~1.6 scheduling rounds -> CUs with 2
// block-lifetimes ran 2T while CUs with 1 idled (~20% makespan waste on a
// BW-bound kernel). 1024 is a single round regardless of 4 or 5 waves/SIMD.
__global__ __launch_bounds__(256) void k_final(FinalArgs a) {
  const int bx = (int)blockIdx.x;
  const bool us = bx < a.blocksU;
  const int*   __restrict__ ids = us ? a.uids : a.iids;
  const float* __restrict__ emb = us ? a.uemb : a.iemb;
  float* __restrict__ outp = us ? a.out : (a.out + (size_t)a.n_user * D);
  const float* __restrict__ Up = a.U + (us ? 0 : 6 * D);
  const int n   = us ? a.n_user : a.n_item;
  const int nb  = us ? a.blocksU : ((int)gridDim.x - a.blocksU);
  const int bid = us ? bx : bx - a.blocksU;

  const int tid   = (int)threadIdx.x;
  const int lane  = tid & 63;
  const int wave  = tid >> 6;
  const int chunk = lane & 15;
  const int rsub  = lane >> 4;

  float4 wv[6], uv[6];
  #pragma unroll
  for (int j = 0; j < 6; ++j) {
    const float* wp = us ? a.wx[j] : a.wy[j];
    wv[j] = reinterpret_cast<const float4*>(wp)[chunk];
    uv[j] = reinterpret_cast<const float4*>(Up + j * D)[chunk];
  }

  const int wavesTotal = nb * 4;
  const int waveId = bid * 4 + wave;
  const int stride = wavesTotal * 8;
  int row = waveId * 8 + rsub;
  int id0 = 0, id1 = 0;
  if (row < n) {
    id0 = ids[row];
    if (row + 4 < n) id1 = ids[row + 4];
  }

  while (row < n) {
    const int nxt = row + stride;
    const bool h1 = (row + 4) < n;          // uniform within each 16-lane group
    const float4 v0 = reinterpret_cast<const float4*>(emb + (size_t)id0 * D)[chunk];
    float4 v1 = make_float4(0.f, 0.f, 0.f, 0.f);
    if (h1) v1 = reinterpret_cast<const float4*>(emb + (size_t)id1 * D)[chunk];
    if (nxt < n) {
      id0 = ids[nxt];
      if (nxt + 4 < n) id1 = ids[nxt + 4];
    }
    float4 r0 = make_float4(0.05f * v0.x, 0.05f * v0.y, 0.05f * v0.z, 0.05f * v0.w);
    float4 r1 = make_float4(0.05f * v1.x, 0.05f * v1.y, 0.05f * v1.z, 0.05f * v1.w);
    #pragma unroll
    for (int j = 0; j < 6; ++j) {
      float d0 = fmaf(v0.x, wv[j].x, fmaf(v0.y, wv[j].y, fmaf(v0.z, wv[j].z, v0.w * wv[j].w)));
      float d1 = fmaf(v1.x, wv[j].x, fmaf(v1.y, wv[j].y, fmaf(v1.z, wv[j].z, v1.w * wv[j].w)));
      d0 += __shfl_xor(d0, 1);  d1 += __shfl_xor(d1, 1);
      d0 += __shfl_xor(d0, 2);  d1 += __shfl_xor(d1, 2);
      d0 += __shfl_xor(d0, 4);  d1 += __shfl_xor(d1, 4);
      d0 += __shfl_xor(d0, 8);  d1 += __shfl_xor(d1, 8);
      r0.x = fmaf(d0, uv[j].x, r0.x);
      r0.y = fmaf(d0, uv[j].y, r0.y);
      r0.z = fmaf(d0, uv[j].z, r0.z);
      r0.w = fmaf(d0, uv[j].w, r0.w);
      r1.x = fmaf(d1, uv[j].x, r1.x);
      r1.y = fmaf(d1, uv[j].y, r1.y);
      r1.z = fmaf(d1, uv[j].z, r1.z);
      r1.w = fmaf(d1, uv[j].w, r1.w);
    }
    nt_store4(outp + (size_t)row * D + chunk * 4, r0);
    if (h1) nt_store4(outp + (size_t)(row + 4) * D + chunk * 4, r1);
    row = nxt;
  }
}

// ---------------- launch ----------------
extern "C" void kernel_launch(void* const* d_in, const int* in_sizes, int n_in,
                              void* d_out, int out_size, void* d_ws, size_t ws_size,
                              hipStream_t stream) {
  (void)n_in; (void)out_size; (void)ws_size;
  const int* uids = (const int*)d_in[0];
  const int* iids = (const int*)d_in[1];
  const float* uemb = (const float*)d_in[2];
  const float* iemb = (const float*)d_in[3];
  const int nu = in_sizes[0], ni = in_sizes[1];

  // _VEC order: buy_uu(0) buy_ui(1) buy_iu(2) buy_ii(3) cart_uu(4) cart_ui(5)
  //             cart_iu(6) cart_ii(7) pv_uu(8) pv_ui(9) pv_iu(10) pv_ii(11)
  // d_in[4+2v] = w, d_in[5+2v] = w1; d_in[28..30] = edges.
  float* S = (float*)d_ws;        // [12][64]
  float* U = S + 768;             // [12][64]
  float* out = (float*)d_out;
  float* edges = out + (size_t)(nu + ni) * D;

  k_init<<<1, 256, 0, stream>>>(S, edges, (const float*)d_in[28],
                                (const float*)d_in[29], (const float*)d_in[30]);

  ReduceArgs ra;
  ra.uids = uids; ra.iids = iids; ra.uemb = uemb; ra.iemb = iemb;
  ra.S = S; ra.n_user = nu; ra.n_item = ni; ra.blocksU = 384;
  {
    const int vu[6] = {0, 4, 8, 2, 6, 10};   // S_x slots 0..5: uu b,c,p then iu b,c,p
    const int vi[6] = {1, 5, 9, 3, 7, 11};   // S_y slots 6..11: ui b,c,p then ii b,c,p
    for (int j = 0; j < 6; ++j) {
      ra.wu[j] = (const float*)d_in[4 + 2 * vu[j]];
      ra.wi[j] = (const float*)d_in[4 + 2 * vi[j]];
    }
  }
  k_reduce<<<1024, 256, 0, stream>>>(ra);

  BuildArgs ba;
  ba.S = S; ba.U = U;
  {
    // q order: x-side [uu b,c,p | ui b,c,p], y-side [ii b,c,p | iu b,c,p]
    const int vq[12]   = {0, 4, 8, 1, 5, 9, 3, 7, 11, 2, 6, 10};
    const int sl[12]   = {0, 1, 2, 6, 7, 8, 9, 10, 11, 3, 4, 5};
    const float wt[3]  = {0.6f, 0.3f, 0.1f};
    for (int q = 0; q < 12; ++q) {
      ba.w1[q] = (const float*)d_in[5 + 2 * vq[q]];
      ba.sslot[q] = sl[q];
      // out = 0.05 e + sum_q (e.w_q) * [0.25 * W * 0.1 * 0.01 * (S_raw @ w1_q)]
      ba.coef[q] = 2.5e-4f * wt[q % 3];
    }
  }
  k_build<<<12, 64, 0, stream>>>(ba);

  FinalArgs fa;
  fa.uids = uids; fa.iids = iids; fa.uemb = uemb; fa.iemb = iemb;
  fa.U = U; fa.out = out;
  fa.n_user = nu; fa.n_item = ni; fa.blocksU = 384;
  {
    const int vx[6] = {0, 4, 8, 1, 5, 9};    // uu b,c,p, ui b,c,p   (pairs U slots 0..5)
    const int vy[6] = {3, 7, 11, 2, 6, 10};  // ii b,c,p, iu b,c,p   (pairs U slots 6..11)
    for (int j = 0; j < 6; ++j) {
      fa.wx[j] = (const float*)d_in[4 + 2 * vx[j]];
      fa.wy[j] = (const float*)d_in[4 + 2 * vy[j]];
    }
  }
  k_final<<<1024, 256, 0, stream>>>(fa);
}

// Round 4
// 445.660 us; speedup vs baseline: 1.0149x; 1.0149x over previous
//
#include <hip/hip_runtime.h>

#define D 64

typedef float f4v __attribute__((ext_vector_type(4)));

static __device__ __forceinline__ void nt_store4(float* p, float4 v) {
  f4v t; t[0] = v.x; t[1] = v.y; t[2] = v.z; t[3] = v.w;
  __builtin_nontemporal_store(t, reinterpret_cast<f4v*>(p));
}

static __device__ __forceinline__ float4 nt_load4(const float* p) {
  f4v t = __builtin_nontemporal_load(reinterpret_cast<const f4v*>(p));
  return make_float4(t[0], t[1], t[2], t[3]);
}

// ---------------- structs ----------------
struct ReduceArgs {
  const int* uids; const int* iids;
  const float* uemb; const float* iemb;
  const float* wu[6]; const float* wi[6];   // per-side w vectors (slot order: uu b,c,p then iu b,c,p / ui b,c,p then ii b,c,p)
  float* S;                                  // [12][64] raw sums over e (un-scaled)
  int n_user, n_item, blocksU;
};

struct BuildArgs {
  const float* S;
  const float* w1[12];   // q order: uu b,c,p | ui b,c,p | ii b,c,p | iu b,c,p
  float* U;              // [12][64]  U_q = 2.5e-4 * W_q * (S[sslot[q]] @ w1_q)
  int sslot[12];
  float coef[12];
};

struct FinalArgs {
  const int* uids; const int* iids;
  const float* uemb; const float* iemb;
  const float* U;                // [12][64]: x-side slots 0..5, y-side slots 6..11
  const float* wx[6];            // uu b,c,p, ui b,c,p
  const float* wy[6];            // ii b,c,p, iu b,c,p
  float* out;
  int n_user, n_item, blocksU;
};

// ---------------- kernel 0: zero S accumulator + copy edge outputs ----------------
__global__ __launch_bounds__(256) void k_init(float* S, float* edges,
                                              const float* be, const float* ce, const float* pe) {
  const int t = threadIdx.x;
  S[t] = 0.f; S[t + 256] = 0.f; S[t + 512] = 0.f;
  if (t < 64)       edges[t] = be[t];
  else if (t < 128) edges[t] = ce[t - 64];
  else if (t < 192) edges[t] = pe[t - 128];
}

// ---------------- kernel 1: S[j] = sum_rows (e . w_j) * e  (raw e) ----------------
// R6: REVERTED to the R1(=R4) 2-chain form. The R5 4-chain variant regressed
// (+6 us): 4x float4 live + 24 wv + 24 acc likely pushed VGPR past the 128
// cliff (4 -> 2 waves/SIMD), LOWERING bytes-in-flight. 2-chain + id prefetch
// stays ~<=96 VGPR -> 4 waves/SIMD.
__global__ __launch_bounds__(256) void k_reduce(ReduceArgs a) {
  const int bx = (int)blockIdx.x;
  const bool us = bx < a.blocksU;
  const int*   __restrict__ ids = us ? a.uids : a.iids;
  const float* __restrict__ emb = us ? a.uemb : a.iemb;
  float* __restrict__ Sout = a.S + (us ? 0 : 6 * D);
  const int n   = us ? a.n_user : a.n_item;
  const int nb  = us ? a.blocksU : ((int)gridDim.x - a.blocksU);
  const int bid = us ? bx : bx - a.blocksU;

  const int tid   = (int)threadIdx.x;
  const int lane  = tid & 63;
  const int wave  = tid >> 6;
  const int chunk = lane & 15;   // which float4 of the row
  const int rsub  = lane >> 4;   // which of 4 rows this wave covers (per half-step)

  float4 wv[6];
  #pragma unroll
  for (int j = 0; j < 6; ++j) {
    const float* wp = us ? a.wu[j] : a.wi[j];
    wv[j] = reinterpret_cast<const float4*>(wp)[chunk];
  }

  float4 acc[6];
  #pragma unroll
  for (int j = 0; j < 6; ++j) acc[j] = make_float4(0.f, 0.f, 0.f, 0.f);

  const int wavesTotal = nb * 4;
  const int waveId = bid * 4 + wave;
  const int stride = wavesTotal * 8;
  int row = waveId * 8 + rsub;
  int id0 = 0, id1 = 0;
  if (row < n) {
    id0 = ids[row];
    if (row + 4 < n) id1 = ids[row + 4];
  }

  while (row < n) {
    const int nxt = row + stride;
    const bool h1 = (row + 4) < n;          // uniform within each 16-lane group
    const float4 v0 = reinterpret_cast<const float4*>(emb + (size_t)id0 * D)[chunk];
    float4 v1 = make_float4(0.f, 0.f, 0.f, 0.f);
    if (h1) v1 = reinterpret_cast<const float4*>(emb + (size_t)id1 * D)[chunk];
    // prefetch next iteration's ids while this iteration computes
    if (nxt < n) {
      id0 = ids[nxt];
      if (nxt + 4 < n) id1 = ids[nxt + 4];
    }
    #pragma unroll
    for (int j = 0; j < 6; ++j) {
      float d0 = fmaf(v0.x, wv[j].x, fmaf(v0.y, wv[j].y, fmaf(v0.z, wv[j].z, v0.w * wv[j].w)));
      float d1 = fmaf(v1.x, wv[j].x, fmaf(v1.y, wv[j].y, fmaf(v1.z, wv[j].z, v1.w * wv[j].w)));
      d0 += __shfl_xor(d0, 1);  d1 += __shfl_xor(d1, 1);
      d0 += __shfl_xor(d0, 2);  d1 += __shfl_xor(d1, 2);
      d0 += __shfl_xor(d0, 4);  d1 += __shfl_xor(d1, 4);
      d0 += __shfl_xor(d0, 8);  d1 += __shfl_xor(d1, 8);
      acc[j].x = fmaf(d1, v1.x, fmaf(d0, v0.x, acc[j].x));
      acc[j].y = fmaf(d1, v1.y, fmaf(d0, v0.y, acc[j].y));
      acc[j].z = fmaf(d1, v1.z, fmaf(d0, v0.z, acc[j].z));
      acc[j].w = fmaf(d1, v1.w, fmaf(d0, v0.w, acc[j].w));
    }
    row = nxt;
  }

  #pragma unroll
  for (int j = 0; j < 6; ++j) {
    acc[j].x += __shfl_xor(acc[j].x, 16); acc[j].x += __shfl_xor(acc[j].x, 32);
    acc[j].y += __shfl_xor(acc[j].y, 16); acc[j].y += __shfl_xor(acc[j].y, 32);
    acc[j].z += __shfl_xor(acc[j].z, 16); acc[j].z += __shfl_xor(acc[j].z, 32);
    acc[j].w += __shfl_xor(acc[j].w, 16); acc[j].w += __shfl_xor(acc[j].w, 32);
  }

  __shared__ __align__(16) float red[4][6][D];
  if (lane < 16) {
    #pragma unroll
    for (int j = 0; j < 6; ++j)
      reinterpret_cast<float4*>(&red[wave][j][0])[chunk] = acc[j];
  }
  __syncthreads();
  // BUGFIX (R2->R3): 384 (j,e) pairs but only 256 threads — previous
  // `if (tid < 384)` never emitted j=4,5, leaving S slots 4,5 / 10,11 zero
  // (exactly the cart/pv iu+ii slots -> y_out err 32.74, x_out unaffected).
  for (int t = tid; t < 384; t += 256) {
    const int j = t >> 6, e = t & 63;
    const float s = red[0][j][e] + red[1][j][e] + red[2][j][e] + red[3][j][e];
    atomicAdd(&Sout[j * D + e], s);
  }
}

// ---------------- kernel 2: U_q = coef_q * (S[sslot_q] @ w1_q)  (12 blocks x 64 thr) ----------------
__global__ __launch_bounds__(64) void k_build(BuildArgs a) {
  const int q = (int)blockIdx.x;
  const int d = (int)threadIdx.x;
  const float* __restrict__ w1 = a.w1[q];
  const float* __restrict__ Sv = a.S + a.sslot[q] * D;
  float s = 0.f;
  for (int k = 0; k < D; ++k) s = fmaf(Sv[k], w1[k * D + d], s);
  a.U[q * D + d] = a.coef[q] * s;
}

// ---------------- kernel 3: out_row = 0.05*e + sum_q (e . w_q) * U_q  (rank-6) ----------------
// R6: kept at 1024 blocks (single residency round). Added non-temporal emb
// loads: emb here is last-use (already L3-hot from k_reduce), nt-load avoids
// re-allocating it in cache on the (rare) miss path. Occupancy-neutral.
__global__ __launch_bounds__(256) void k_final(FinalArgs a) {
  const int bx = (int)blockIdx.x;
  const bool us = bx < a.blocksU;
  const int*   __restrict__ ids = us ? a.uids : a.iids;
  const float* __restrict__ emb = us ? a.uemb : a.iemb;
  float* __restrict__ outp = us ? a.out : (a.out + (size_t)a.n_user * D);
  const float* __restrict__ Up = a.U + (us ? 0 : 6 * D);
  const int n   = us ? a.n_user : a.n_item;
  const int nb  = us ? a.blocksU : ((int)gridDim.x - a.blocksU);
  const int bid = us ? bx : bx - a.blocksU;

  const int tid   = (int)threadIdx.x;
  const int lane  = tid & 63;
  const int wave  = tid >> 6;
  const int chunk = lane & 15;
  const int rsub  = lane >> 4;

  float4 wv[6], uv[6];
  #pragma unroll
  for (int j = 0; j < 6; ++j) {
    const float* wp = us ? a.wx[j] : a.wy[j];
    wv[j] = reinterpret_cast<const float4*>(wp)[chunk];
    uv[j] = reinterpret_cast<const float4*>(Up + j * D)[chunk];
  }

  const int wavesTotal = nb * 4;
  const int waveId = bid * 4 + wave;
  const int stride = wavesTotal * 8;
  int row = waveId * 8 + rsub;
  int id0 = 0, id1 = 0;
  if (row < n) {
    id0 = ids[row];
    if (row + 4 < n) id1 = ids[row + 4];
  }

  while (row < n) {
    const int nxt = row + stride;
    const bool h1 = (row + 4) < n;          // uniform within each 16-lane group
    const float4 v0 = nt_load4(emb + (size_t)id0 * D + chunk * 4);
    float4 v1 = make_float4(0.f, 0.f, 0.f, 0.f);
    if (h1) v1 = nt_load4(emb + (size_t)id1 * D + chunk * 4);
    if (nxt < n) {
      id0 = ids[nxt];
      if (nxt + 4 < n) id1 = ids[nxt + 4];
    }
    float4 r0 = make_float4(0.05f * v0.x, 0.05f * v0.y, 0.05f * v0.z, 0.05f * v0.w);
    float4 r1 = make_float4(0.05f * v1.x, 0.05f * v1.y, 0.05f * v1.z, 0.05f * v1.w);
    #pragma unroll
    for (int j = 0; j < 6; ++j) {
      float d0 = fmaf(v0.x, wv[j].x, fmaf(v0.y, wv[j].y, fmaf(v0.z, wv[j].z, v0.w * wv[j].w)));
      float d1 = fmaf(v1.x, wv[j].x, fmaf(v1.y, wv[j].y, fmaf(v1.z, wv[j].z, v1.w * wv[j].w)));
      d0 += __shfl_xor(d0, 1);  d1 += __shfl_xor(d1, 1);
      d0 += __shfl_xor(d0, 2);  d1 += __shfl_xor(d1, 2);
      d0 += __shfl_xor(d0, 4);  d1 += __shfl_xor(d1, 4);
      d0 += __shfl_xor(d0, 8);  d1 += __shfl_xor(d1, 8);
      r0.x = fmaf(d0, uv[j].x, r0.x);
      r0.y = fmaf(d0, uv[j].y, r0.y);
      r0.z = fmaf(d0, uv[j].z, r0.z);
      r0.w = fmaf(d0, uv[j].w, r0.w);
      r1.x = fmaf(d1, uv[j].x, r1.x);
      r1.y = fmaf(d1, uv[j].y, r1.y);
      r1.z = fmaf(d1, uv[j].z, r1.z);
      r1.w = fmaf(d1, uv[j].w, r1.w);
    }
    nt_store4(outp + (size_t)row * D + chunk * 4, r0);
    if (h1) nt_store4(outp + (size_t)(row + 4) * D + chunk * 4, r1);
    row = nxt;
  }
}

// ---------------- launch ----------------
extern "C" void kernel_launch(void* const* d_in, const int* in_sizes, int n_in,
                              void* d_out, int out_size, void* d_ws, size_t ws_size,
                              hipStream_t stream) {
  (void)n_in; (void)out_size; (void)ws_size;
  const int* uids = (const int*)d_in[0];
  const int* iids = (const int*)d_in[1];
  const float* uemb = (const float*)d_in[2];
  const float* iemb = (const float*)d_in[3];
  const int nu = in_sizes[0], ni = in_sizes[1];

  // _VEC order: buy_uu(0) buy_ui(1) buy_iu(2) buy_ii(3) cart_uu(4) cart_ui(5)
  //             cart_iu(6) cart_ii(7) pv_uu(8) pv_ui(9) pv_iu(10) pv_ii(11)
  // d_in[4+2v] = w, d_in[5+2v] = w1; d_in[28..30] = edges.
  float* S = (float*)d_ws;        // [12][64]
  float* U = S + 768;             // [12][64]
  float* out = (float*)d_out;
  float* edges = out + (size_t)(nu + ni) * D;

  k_init<<<1, 256, 0, stream>>>(S, edges, (const float*)d_in[28],
                                (const float*)d_in[29], (const float*)d_in[30]);

  ReduceArgs ra;
  ra.uids = uids; ra.iids = iids; ra.uemb = uemb; ra.iemb = iemb;
  ra.S = S; ra.n_user = nu; ra.n_item = ni; ra.blocksU = 384;
  {
    const int vu[6] = {0, 4, 8, 2, 6, 10};   // S_x slots 0..5: uu b,c,p then iu b,c,p
    const int vi[6] = {1, 5, 9, 3, 7, 11};   // S_y slots 6..11: ui b,c,p then ii b,c,p
    for (int j = 0; j < 6; ++j) {
      ra.wu[j] = (const float*)d_in[4 + 2 * vu[j]];
      ra.wi[j] = (const float*)d_in[4 + 2 * vi[j]];
    }
  }
  k_reduce<<<1024, 256, 0, stream>>>(ra);

  BuildArgs ba;
  ba.S = S; ba.U = U;
  {
    // q order: x-side [uu b,c,p | ui b,c,p], y-side [ii b,c,p | iu b,c,p]
    const int vq[12]   = {0, 4, 8, 1, 5, 9, 3, 7, 11, 2, 6, 10};
    const int sl[12]   = {0, 1, 2, 6, 7, 8, 9, 10, 11, 3, 4, 5};
    const float wt[3]  = {0.6f, 0.3f, 0.1f};
    for (int q = 0; q < 12; ++q) {
      ba.w1[q] = (const float*)d_in[5 + 2 * vq[q]];
      ba.sslot[q] = sl[q];
      // out = 0.05 e + sum_q (e.w_q) * [0.25 * W * 0.1 * 0.01 * (S_raw @ w1_q)]
      ba.coef[q] = 2.5e-4f * wt[q % 3];
    }
  }
  k_build<<<12, 64, 0, stream>>>(ba);

  FinalArgs fa;
  fa.uids = uids; fa.iids = iids; fa.uemb = uemb; fa.iemb = iemb;
  fa.U = U; fa.out = out;
  fa.n_user = nu; fa.n_item = ni; fa.blocksU = 384;
  {
    const int vx[6] = {0, 4, 8, 1, 5, 9};    // uu b,c,p, ui b,c,p   (pairs U slots 0..5)
    const int vy[6] = {3, 7, 11, 2, 6, 10};  // ii b,c,p, iu b,c,p   (pairs U slots 6..11)
    for (int j = 0; j < 6; ++j) {
      fa.wx[j] = (const float*)d_in[4 + 2 * vx[j]];
      fa.wy[j] = (const float*)d_in[4 + 2 * vy[j]];
    }
  }
  k_final<<<1024, 256, 0, stream>>>(fa);
}